// Round 1
// 317.019 us; speedup vs baseline: 1.0078x; 1.0078x over previous
//
#include <hip/hip_runtime.h>
#include <math.h>

#define DD 8
#define BB 4096
#define VV 1024
#define K_SEL 102
#define RPB 4            // rows (waves) per block

// order-preserving float <-> uint key maps (bijective, exact)
__device__ __forceinline__ unsigned f2key(float f) {
    unsigned u = __float_as_uint(f);
    unsigned m = (unsigned)((int)u >> 31) | 0x80000000u;  // neg: FFFFFFFF, pos: 80000000
    return u ^ m;
}
__device__ __forceinline__ float key2f(unsigned k) {
    unsigned m = 0x80000000u | ~((unsigned)((int)k >> 31)); // top set: 80000000, else FFFFFFFF
    return __uint_as_float(k ^ m);
}

// One WAVE per (d,b) row: 16 elems/lane, wave-private LDS histogram, no __syncthreads.
// v2: 2 radix passes (top 16 bits) + direct wave-max selection on the tiny surviving
//     bucket; float cache fv[16] kills key2f recompute; gumbel argmax via exact
//     fraction compare p/(-log u) -> one log per element, no lz/mlz needed.
__global__ __launch_bounds__(256) void decode_row_kernel(
    const float* __restrict__ logits,
    const float* __restrict__ unoise,
    const int* __restrict__ curvals,
    float* __restrict__ probs_out,   // [D*B*V]
    int* __restrict__ samples)       // [D*B] workspace
{
    const int wave = threadIdx.x >> 6;
    const int lane = threadIdx.x & 63;
    const int row  = blockIdx.x * RPB + wave;

    // 4 replica histograms per wave, replica stride 260 dwords (bank-shifted by 4).
    __shared__ __align__(16) unsigned hist[RPB][1040];
    unsigned* h = hist[wave];

    const float4* l4 = (const float4*)(logits + (size_t)row * VV);
    const float4* u4 = (const float4*)(unoise + (size_t)row * VV);
    const int cv1 = max(curvals[row], 1);   // index 0 always masked -> fold into one cmp

    // ---- load + mask; keep both float and order-key forms ----
    unsigned key[16];
    float    fv[16];
#pragma unroll
    for (int i = 0; i < 4; i++) {
        float4 ff = l4[i * 64 + lane];
        const int vb = i * 256 + lane * 4;
        float e[4] = {ff.x, ff.y, ff.z, ff.w};
#pragma unroll
        for (int j = 0; j < 4; j++) {
            int v = vb + j;
            float t = (v < cv1) ? -INFINITY : e[j];
            fv[i * 4 + j]  = t;
            key[i * 4 + j] = f2key(t);
        }
    }

    // ---- exact radix select on top 16 bits (2 x 8-bit passes) ----
    unsigned prefix = 0;
    unsigned kk = K_SEL;
    const int rep = (lane & 3) * 260;
#pragma unroll
    for (int pass = 0; pass < 2; pass++) {
        const int shift = 24 - 8 * pass;
        const uint4 z = {0u, 0u, 0u, 0u};
#pragma unroll
        for (int r = 0; r < 4; r++)
            ((uint4*)(h + r * 260))[lane] = z;   // lane clears its 4 owned digits, all reps
        __builtin_amdgcn_wave_barrier();
        // branchless feed: inactive elements add 0 to a harmless bin (no exec churn)
#pragma unroll
        for (int i = 0; i < 16; i++) {
            unsigned t = (key[i] ^ prefix) >> shift;
            unsigned inc = (pass == 0) ? 1u : (t < 256u ? 1u : 0u);
            atomicAdd(h + rep + (t & 0xFFu), inc);
        }
        __threadfence_block();                    // order atomics before reads (in-wave)
        __builtin_amdgcn_wave_barrier();
        uint4 c0 = ((uint4*)(h + 0 * 260))[lane];
        uint4 c1 = ((uint4*)(h + 1 * 260))[lane];
        uint4 c2 = ((uint4*)(h + 2 * 260))[lane];
        uint4 c3 = ((uint4*)(h + 3 * 260))[lane];
        __builtin_amdgcn_wave_barrier();
        unsigned cnt0 = c0.x + c1.x + c2.x + c3.x;
        unsigned cnt1 = c0.y + c1.y + c2.y + c3.y;
        unsigned cnt2 = c0.z + c1.z + c2.z + c3.z;
        unsigned cnt3 = c0.w + c1.w + c2.w + c3.w;
        // local suffix sums over lane's 4 digits (digit 4*lane+j)
        unsigned s3 = cnt3;
        unsigned s2 = cnt2 + s3;
        unsigned s1 = cnt1 + s2;
        unsigned s0 = cnt0 + s1;
        // wave inclusive suffix scan of per-lane totals
        unsigned suf = s0;
#pragma unroll
        for (int off = 1; off < 64; off <<= 1) {
            unsigned o = __shfl_down(suf, off, 64);
            suf += (lane + off < 64) ? o : 0u;
        }
        const unsigned above = suf - s0;          // count in digits owned by lanes > lane
        // find the unique digit with gt < kk <= ge
        unsigned sel = 0u;
        bool found = false;
        {
            unsigned ge, gt;
            ge = s0 + above; gt = ge - cnt0;
            if (ge >= kk && gt < kk) { found = true; sel = ((unsigned)(lane * 4 + 0) << 16) | (kk - gt); }
            ge = s1 + above; gt = ge - cnt1;
            if (ge >= kk && gt < kk) { found = true; sel = ((unsigned)(lane * 4 + 1) << 16) | (kk - gt); }
            ge = s2 + above; gt = ge - cnt2;
            if (ge >= kk && gt < kk) { found = true; sel = ((unsigned)(lane * 4 + 2) << 16) | (kk - gt); }
            ge = s3 + above; gt = ge - cnt3;
            if (ge >= kk && gt < kk) { found = true; sel = ((unsigned)(lane * 4 + 3) << 16) | (kk - gt); }
        }
        unsigned long long bal = __ballot(found);
        int src = __ffsll((unsigned long long)bal) - 1;
        sel = __shfl(sel, src, 64);
        prefix |= (sel >> 16) << shift;
        kk = sel & 0xFFFFu;
        __builtin_amdgcn_wave_barrier();
    }

    // ---- finish: kk-th largest within the 16-bit prefix bucket (tiny for iid data) ----
    // Invariant from radix: bucket holds >= kk elements; loop removes >=1 per iter.
    unsigned cmask = 0u;
#pragma unroll
    for (int i = 0; i < 16; i++)
        if ((key[i] & 0xFFFF0000u) == prefix) cmask |= (1u << i);
    unsigned thr;
    for (;;) {
        unsigned mx = 0u;
#pragma unroll
        for (int i = 0; i < 16; i++)
            if (cmask & (1u << i)) mx = max(mx, key[i]);
#pragma unroll
        for (int off = 32; off; off >>= 1)
            mx = max(mx, (unsigned)__shfl_xor((int)mx, off, 64));
        if (kk <= 1u) { thr = mx; break; }
        // count elements equal to current max (equal keys share the prefix -> candidates)
        unsigned ceq = 0u;
#pragma unroll
        for (int i = 0; i < 16; i++)
            if (key[i] == mx) ceq++;
#pragma unroll
        for (int off = 32; off; off >>= 1)
            ceq += (unsigned)__shfl_xor((int)ceq, off, 64);
        if (kk <= ceq) { thr = mx; break; }
        kk -= ceq;
#pragma unroll
        for (int i = 0; i < 16; i++)
            if (key[i] == mx) cmask &= ~(1u << i);
    }
    const float thrf = key2f(thr);   // exact value of the K_SEL-th largest masked logit

    // ---- row max (float, butterfly) ----
    float m = fv[0];
#pragma unroll
    for (int i = 1; i < 16; i++) m = fmaxf(m, fv[i]);
#pragma unroll
    for (int off = 32; off; off >>= 1)
        m = fmaxf(m, __shfl_xor(m, off, 64));

    // ---- sum of exp over kept elements ----
    float ex[16];
    float s = 0.0f;
#pragma unroll
    for (int i = 0; i < 16; i++) {
        float e = (fv[i] >= thrf) ? __expf(fv[i] - m) : 0.0f;
        ex[i] = e;
        s += e;
    }
    // prefetch noise while the reduction chain drains
    float4 uu[4];
#pragma unroll
    for (int i = 0; i < 4; i++) uu[i] = u4[i * 64 + lane];
#pragma unroll
    for (int off = 32; off; off >>= 1)
        s += __shfl_xor(s, off, 64);
    const float inv = 1.0f / s;

    // ---- probs write + gumbel-max argmax via fraction compare ----
    // argmax(logp + g) == argmax(p / (-log u)) ; compare a/nl > bn/bd by cross-mul.
    float bnum = 0.0f, bden = 1.0f;
    int   besti = VV;
    float4* p4 = (float4*)(probs_out + (size_t)row * VV);
#pragma unroll
    for (int i = 0; i < 4; i++) {
        float4 pv;
        pv.x = ex[i * 4 + 0] * inv;
        pv.y = ex[i * 4 + 1] * inv;
        pv.z = ex[i * 4 + 2] * inv;
        pv.w = ex[i * 4 + 3] * inv;
        p4[i * 64 + lane] = pv;
        float us[4] = {uu[i].x, uu[i].y, uu[i].z, uu[i].w};
#pragma unroll
        for (int j = 0; j < 4; j++) {
            const int idx = i * 4 + j;
            float nl = 1e-20f - __logf(us[j] + 1e-20f);   // -log(u+eps)+eps > 0
            float a  = ex[idx];                            // 0 for filtered -> never wins
            int v = i * 256 + lane * 4 + j;
            if (a * bden > bnum * nl) { bnum = a; bden = nl; besti = v; }  // strict >: earliest v in-lane
        }
    }
#pragma unroll
    for (int off = 32; off; off >>= 1) {
        float onum = __shfl_xor(bnum, off, 64);
        float oden = __shfl_xor(bden, off, 64);
        int   oi   = __shfl_xor(besti, off, 64);
        float x = onum * bden, y = bnum * oden;
        if (x > y || (x == y && oi < besti)) { bnum = onum; bden = oden; besti = oi; }
    }
    if (lane == 0) samples[row] = besti;
}

// tokens[b*D + d] = (d==0 || samples[b]==NOTE_TYPE) ? samples[d*B+b] : 0
__global__ __launch_bounds__(256) void tokens_kernel(
    const int* __restrict__ samples, float* __restrict__ tokens_out)
{
    int i = blockIdx.x * 256 + threadIdx.x;   // exactly B*D threads
    int b = i >> 3;
    int d = i & 7;
    int sm = samples[d * BB + b];
    int t0 = samples[b];
    tokens_out[i] = (d == 0 || t0 == 1) ? (float)sm : 0.0f;
}

extern "C" void kernel_launch(void* const* d_in, const int* in_sizes, int n_in,
                              void* d_out, int out_size, void* d_ws, size_t ws_size,
                              hipStream_t stream) {
    const float* logits = (const float*)d_in[0];
    const float* unoise = (const float*)d_in[1];
    const int*   curvals = (const int*)d_in[2];

    float* out        = (float*)d_out;
    float* tokens_out = out;                       // [B*D]
    float* probs_out  = out + (size_t)BB * DD;     // [D*B*V]
    int*   samples    = (int*)d_ws;                // [D*B]

    decode_row_kernel<<<(DD * BB) / RPB, 256, 0, stream>>>(logits, unoise, curvals,
                                                           probs_out, samples);
    tokens_kernel<<<(BB * DD) / 256, 256, 0, stream>>>(samples, tokens_out);
}